// Round 8
// baseline (7518.634 us; speedup 1.0000x reference)
//
#include <hip/hip_runtime.h>

#define DEV __device__ __forceinline__

typedef _Float16 f16x8 __attribute__((ext_vector_type(8)));
typedef float f32x4 __attribute__((ext_vector_type(4)));

// ---- problem dims ----
constexpr int B_ = 256, A_ = 20, T_ = 50, IN_ = 6;
constexpr int H_ = 256, G_ = 1024, NH_ = 8, DT_ = 60;
constexpr int NN_ = 19;
constexpr int NB_ = B_ * NN_;   // 4864
constexpr int XROW = T_ * IN_;  // 300

// encoder: M=32/block. 160 blocks = 152 nbr + 8 ego.
constexpr int NBLK_ENC = 160;
// decoder: M=16/block, 16 blocks
constexpr int NBLK_DEC = 16;

// ---- ws byte offsets ----
// B-fragment layout for W^T (j=gate*256+col): frag[((jt*8+kt)*64+l)*8+e]
//   = (fp16) W[n*256+k], n=jt*16+(l&15), k=kt*32+(l>>4)*8+e
constexpr size_t FB = 64ull * 8 * 64 * 8 * 2;  // 512KB per 1024x256 matrix
constexpr size_t FS = 64ull * 64 * 8 * 2;      // 64KB per 1024x6 (K pad 32)
constexpr size_t O_F_NHH0 = 0;
constexpr size_t O_F_NIH1 = O_F_NHH0 + FB;
constexpr size_t O_F_NHH1 = O_F_NIH1 + FB;
constexpr size_t O_F_EHH0 = O_F_NHH1 + FB;
constexpr size_t O_F_EIH1 = O_F_EHH0 + FB;
constexpr size_t O_F_EHH1 = O_F_EIH1 + FB;
constexpr size_t O_F_DHH0 = O_F_EHH1 + FB;
constexpr size_t O_F_DIH1 = O_F_DHH0 + FB;
constexpr size_t O_F_DHH1 = O_F_DIH1 + FB;
constexpr size_t O_F_NIH0 = O_F_DHH1 + FB;
constexpr size_t O_F_EIH0 = O_F_NIH0 + FS;
constexpr size_t B_BC    = O_F_EIH0 + FS;            // 6*1024 fp32
constexpr size_t B_ATT   = B_BC + 6 * 1024 * 4;      // 4 x [k][256] fp32
constexpr size_t B_WCT   = B_ATT + 4 * 65536 * 4;    // [2][512][256] fp32
constexpr size_t B_DIH0T = B_WCT + 2 * 512 * 256 * 4;// [k][1024] fp32
constexpr size_t B_NBRH1 = B_DIH0T + 256 * 1024 * 4; // [2][4864][256] fp32
constexpr size_t B_COMB  = B_NBRH1 + 2ull * NB_ * H_ * 4;  // [2][256][512]
constexpr size_t B_PRE0  = B_COMB + 2ull * B_ * 512 * 4;   // [256][1024]

struct Par {
  const float* x;
  const float* big_src[10];
  const float* ih0_src[2];
  const float* att_src[4];
  const float* Wconv;
  const float* bih[6];
  const float* bhh[6];
  const float *bq, *bk, *bv, *bao, *bconv, *Wout, *bout;
  float* ws;
  float* out;
};

// ---------------- prep: fragment packing + transposes + bias sums ----------------
__global__ void prep_kernel(Par p) {
  char* wsb = (char*)p.ws;
  const size_t NBIG = 9ull * 262144;
  const size_t NIH0 = 2ull * 32768;
  const size_t NBC  = 6144;
  const size_t NATT = 4ull * 65536;
  const size_t NWCT = 2ull * 512 * 256;
  const size_t NDIH = 256ull * 1024;
  const size_t total = NBIG + NIH0 + NBC + NATT + NWCT + NDIH;
  for (size_t i = (size_t)blockIdx.x * blockDim.x + threadIdx.x; i < total;
       i += (size_t)gridDim.x * blockDim.x) {
    size_t idx = i;
    if (idx < NBIG) {
      int mi = (int)(idx / 262144);
      size_t f = idx - (size_t)mi * 262144;
      int e = (int)(f & 7), l = (int)((f >> 3) & 63);
      int kt = (int)((f >> 9) & 7), jt = (int)(f >> 12);
      int n = jt * 16 + (l & 15), k = kt * 32 + (l >> 4) * 8 + e;
      ((_Float16*)(wsb + O_F_NHH0))[idx] =
          (_Float16)p.big_src[mi][(size_t)n * 256 + k];
      continue;
    }
    idx -= NBIG;
    if (idx < NIH0) {
      int mi = (int)(idx >> 15);
      size_t f = idx & 32767;
      int e = (int)(f & 7), l = (int)((f >> 3) & 63), jt = (int)(f >> 9);
      int n = jt * 16 + (l & 15), k = (l >> 4) * 8 + e;
      ((_Float16*)(wsb + O_F_NIH0))[idx] =
          (_Float16)(k < 6 ? p.ih0_src[mi][(size_t)n * 6 + k] : 0.f);
      continue;
    }
    idx -= NIH0;
    if (idx < NBC) {
      int li = (int)(idx >> 10), jj = (int)(idx & 1023);
      ((float*)(wsb + B_BC))[idx] = p.bih[li][jj] + p.bhh[li][jj];
      continue;
    }
    idx -= NBC;
    if (idx < NATT) {
      int mi = (int)(idx >> 16);
      size_t f = idx & 65535;
      int k = (int)(f >> 8), c = (int)(f & 255);
      ((float*)(wsb + B_ATT))[idx] = p.att_src[mi][(size_t)c * 256 + k];
      continue;
    }
    idx -= NATT;
    if (idx < NWCT) {
      int dt = (int)(idx / (512 * 256));
      size_t f = idx - (size_t)dt * 512 * 256;
      int c = (int)(f >> 8), o = (int)(f & 255);
      ((float*)(wsb + B_WCT))[idx] = p.Wconv[(size_t)o * 1536 + (size_t)c * 3 + dt];
      continue;
    }
    idx -= NWCT;
    {
      int k = (int)(idx >> 10), j = (int)(idx & 1023);
      ((float*)(wsb + B_DIH0T))[idx] = p.big_src[9][(size_t)j * 256 + k];
    }
  }
}

// ---------------- building blocks ----------------
DEV float fsig(float x) { return 1.f / (1.f + __expf(-x)); }
DEV float ftanh(float x) { return 1.f - 2.f / (__expf(2.f * x) + 1.f); }

DEV void loadB8(f16x8 (&dst)[8], const _Float16* __restrict__ WB, int kt,
                int w, int l) {
#pragma unroll
  for (int q = 0; q < 8; ++q) {
    int jt = (q >> 1) * 16 + w * 2 + (q & 1);
    dst[q] = *(const f16x8*)(WB + ((size_t)(jt * 8 + kt) * 64 + l) * 8);
  }
}
DEV void loadB8_ih0(f16x8 (&dst)[8], const _Float16* __restrict__ WB, int w,
                    int l) {
#pragma unroll
  for (int q = 0; q < 8; ++q) {
    int jt = (q >> 1) * 16 + w * 2 + (q & 1);
    dst[q] = *(const f16x8*)(WB + ((size_t)jt * 64 + l) * 8);
  }
}

template <int MT>
DEV void mm_chunk(f32x4 (&acc)[MT][4][2], const _Float16* Hhi,
                  const _Float16* Hlo, int kt, const f16x8 (&bb)[8], int m15,
                  int khi) {
  f16x8 ah[MT], al[MT];
#pragma unroll
  for (int mt = 0; mt < MT; ++mt) {
    int off = (mt * 16 + m15) * 264 + kt * 32 + khi;
    ah[mt] = *(const f16x8*)(Hhi + off);
    al[mt] = *(const f16x8*)(Hlo + off);
  }
#pragma unroll
  for (int q = 0; q < 8; ++q) {
    int g = q >> 1, t2 = q & 1;
#pragma unroll
    for (int mt = 0; mt < MT; ++mt) {
      acc[mt][g][t2] = __builtin_amdgcn_mfma_f32_16x16x32_f16(
          ah[mt], bb[q], acc[mt][g][t2], 0, 0, 0);
      acc[mt][g][t2] = __builtin_amdgcn_mfma_f32_16x16x32_f16(
          al[mt], bb[q], acc[mt][g][t2], 0, 0, 0);
    }
  }
}

template <int MT>
DEV void acc_init(f32x4 (&acc)[MT][4][2], const float (&b)[4][2]) {
#pragma unroll
  for (int mt = 0; mt < MT; ++mt)
#pragma unroll
    for (int g = 0; g < 4; ++g)
#pragma unroll
      for (int t2 = 0; t2 < 2; ++t2) {
        f32x4 v = {b[g][t2], b[g][t2], b[g][t2], b[g][t2]};
        acc[mt][g][t2] = v;
      }
}

template <int MT>
DEV void cell_compute(f32x4 (&acc)[MT][4][2], f32x4 (&c)[MT][2],
                      float (&hv)[MT][2][4]) {
#pragma unroll
  for (int mt = 0; mt < MT; ++mt)
#pragma unroll
    for (int t2 = 0; t2 < 2; ++t2)
#pragma unroll
      for (int r = 0; r < 4; ++r) {
        float iv = fsig(acc[mt][0][t2][r]);
        float fv = fsig(acc[mt][1][t2][r]);
        float gv = ftanh(acc[mt][2][t2][r]);
        float ov = fsig(acc[mt][3][t2][r]);
        float cv = fv * c[mt][t2][r] + iv * gv;
        c[mt][t2][r] = cv;
        hv[mt][t2][r] = ov * ftanh(cv);
      }
}

template <int MT>
DEV void writeH(const float (&hv)[MT][2][4], _Float16* Hhi, _Float16* Hlo,
                int w, int l) {
  const int rbase = (l >> 4) * 4, m15 = l & 15;
#pragma unroll
  for (int mt = 0; mt < MT; ++mt)
#pragma unroll
    for (int t2 = 0; t2 < 2; ++t2)
#pragma unroll
      for (int r = 0; r < 4; ++r) {
        int m = mt * 16 + rbase + r, col = w * 32 + t2 * 16 + m15;
        float hvv = hv[mt][t2][r];
        _Float16 hi = (_Float16)hvv;
        Hhi[m * 264 + col] = hi;
        Hlo[m * 264 + col] = (_Float16)(hvv - (float)hi);
      }
}

// depth-2 chunk: prefetch (WBn,ktn) into bload 2 chunks ahead; consume bcons
#define CHUNKD(bcons, bload, WBn, ktn, Hhi, Hlo, kt)  \
  loadB8(bload, WBn, ktn, w, l);                      \
  mm_chunk<MTC>(acc, Hhi, Hlo, kt, bcons, m15, khi);
// 8-chunk group, 3-bank rotation. Entry: x=kt0 (resident/in-flight), y=kt1
// (in flight), z=free. Exit: z=WBn kt0, x=WBn kt1, y=free -> next group is
// G8D(z, x, y, ...).
#define G8D(x, y, z, WBc, WBn, Hhi, Hlo)   \
  CHUNKD(x, z, WBc, 2, Hhi, Hlo, 0)        \
  CHUNKD(y, x, WBc, 3, Hhi, Hlo, 1)        \
  CHUNKD(z, y, WBc, 4, Hhi, Hlo, 2)        \
  CHUNKD(x, z, WBc, 5, Hhi, Hlo, 3)        \
  CHUNKD(y, x, WBc, 6, Hhi, Hlo, 4)        \
  CHUNKD(z, y, WBc, 7, Hhi, Hlo, 5)        \
  CHUNKD(x, z, WBn, 0, Hhi, Hlo, 6)        \
  CHUNKD(y, x, WBn, 1, Hhi, Hlo, 7)

// ---------------- encoder: fused ego+nbr 2-layer LSTM (MFMA, depth-2 pipelined) --
// waves_per_eu(2,2): compiler budget 256 VGPR/wave (512-thread block = 2 waves/EU).
// LDS pad pushes block >80KB -> 1 block/CU, so the LDS-derived occupancy target
// agrees (belt and suspenders vs the r4/r6 observed 128-VGPR cap).
__attribute__((amdgpu_waves_per_eu(2, 2))) __global__ __launch_bounds__(512)
void encoder_kernel(Par p) {
  constexpr int MTC = 2;
  __shared__ _Float16 Hs[2][2][32][264];  // [layer][hi/lo][m][k pad]
  __shared__ _Float16 XF[2][512];         // [mt][lane*8] A-frag of x (K pad 32)
  __shared__ _Float16 pad_[8192];         // occupancy control (see above)
  const int tid = threadIdx.x, w = tid >> 6, l = tid & 63;
  const int m15 = l & 15, khi = (l >> 4) * 8;
  const int bid = blockIdx.x;
  const bool ego = ((bid & 7) == 0) && (bid < 64);
  int nid = 0, eidx = 0;
  if (ego) {
    eidx = bid >> 3;
  } else {
    int nb = (bid + 7) >> 3;
    if (nb > 8) nb = 8;
    nid = bid - nb;
  }
  char* wsb = (char*)p.ws;
  const _Float16* WB_hh0 = (const _Float16*)(wsb + (ego ? O_F_EHH0 : O_F_NHH0));
  const _Float16* WB_ih1 = (const _Float16*)(wsb + (ego ? O_F_EIH1 : O_F_NIH1));
  const _Float16* WB_hh1 = (const _Float16*)(wsb + (ego ? O_F_EHH1 : O_F_NHH1));
  const _Float16* WB_ih0 = (const _Float16*)(wsb + (ego ? O_F_EIH0 : O_F_NIH0));

  if (tid == 0) ((volatile _Float16*)pad_)[0] = (_Float16)0.f;
  for (int i = tid; i < 2 * 2 * 32 * 264; i += 512)
    ((_Float16*)Hs)[i] = (_Float16)0.f;
  for (int i = tid; i < 1024; i += 512) ((_Float16*)XF)[i] = (_Float16)0.f;

  const float* bcb = (const float*)(wsb + B_BC) + (ego ? 2048 : 0);
  float b0v[4][2], b1v[4][2];
#pragma unroll
  for (int g = 0; g < 4; ++g)
#pragma unroll
    for (int t2 = 0; t2 < 2; ++t2) {
      int j = g * 256 + w * 32 + t2 * 16 + m15;
      b0v[g][t2] = bcb[j];
      b1v[g][t2] = bcb[1024 + j];
    }

  // x staging: tid<192 -> (m32 0..31, kx 0..5)
  const int m32 = tid / 6, kx = tid - m32 * 6;
  const float* xp = nullptr;
  int xslot = 0;
  if (tid < 192) {
    int row;
    if (!ego) {
      int n = nid * 32 + m32;
      int q = n / 19;
      row = q * 20 + 1 + (n - q * 19);
    } else {
      row = (eidx * 32 + m32) * 20;
    }
    xp = p.x + (size_t)row * XROW + kx;
    xslot = (m32 >> 4) * 512 + (m32 & 15) * 8 + kx;
  }

  __syncthreads();
  if (tid < 192) ((_Float16*)XF)[xslot] = (_Float16)xp[0];

  f16x8 bA[8], bB[8], bC[8];
  loadB8(bA, WB_hh0, 0, w, l);    // hh0 kt0
  loadB8(bB, WB_hh0, 1, w, l);    // hh0 kt1
  loadB8_ih0(bC, WB_ih0, w, l);   // ih0 (single-kt matrix)
  __syncthreads();

  f32x4 c0[2][2] = {}, c1[2][2] = {};
  float h0v[2][2][4], h1v[2][2][4];

  for (int t = 0; t < T_; ++t) {
    // ---- layer 0 ----
    f32x4 acc[MTC][4][2];
    acc_init<MTC>(acc, b0v);
    {  // ih0 chunk: consume bC (refilled at end of previous iteration)
      f16x8 a0 = *(const f16x8*)(&XF[0][l * 8]);
      f16x8 a1 = *(const f16x8*)(&XF[1][l * 8]);
#pragma unroll
      for (int q = 0; q < 8; ++q) {
        acc[0][q >> 1][q & 1] = __builtin_amdgcn_mfma_f32_16x16x32_f16(
            a0, bC[q], acc[0][q >> 1][q & 1], 0, 0, 0);
        acc[1][q >> 1][q & 1] = __builtin_amdgcn_mfma_f32_16x16x32_f16(
            a1, bC[q], acc[1][q >> 1][q & 1], 0, 0, 0);
      }
    }
    G8D(bA, bB, bC, WB_hh0, WB_ih1, &Hs[0][0][0][0], &Hs[0][1][0][0])
    cell_compute<MTC>(acc, c0, h0v);
    __syncthreads();  // B1: all reads of Hs[0] done
    writeH<MTC>(h0v, &Hs[0][0][0][0], &Hs[0][1][0][0], w, l);
    if (t < T_ - 1 && tid < 192)
      ((_Float16*)XF)[xslot] = (_Float16)xp[(t + 1) * IN_];
    __syncthreads();  // B2: h0_new + x_{t+1} visible

    // ---- layer 1 ----
    acc_init<MTC>(acc, b1v);
    G8D(bC, bA, bB, WB_ih1, WB_hh1, &Hs[0][0][0][0], &Hs[0][1][0][0])  // h0 NEW
    G8D(bB, bC, bA, WB_hh1, WB_hh0, &Hs[1][0][0][0], &Hs[1][1][0][0])  // h1 OLD
    loadB8_ih0(bC, WB_ih0, w, l);  // refill ih0 for next step (bC free here)
    cell_compute<MTC>(acc, c1, h1v);
    __syncthreads();  // B3: reads of Hs[1] done
    writeH<MTC>(h1v, &Hs[1][0][0][0], &Hs[1][1][0][0], w, l);
    if (t >= T_ - 2) {  // only t=48,49 consumed downstream
      int tg = t - (T_ - 2);
      const int rbase = (l >> 4) * 4;
#pragma unroll
      for (int mt = 0; mt < 2; ++mt)
#pragma unroll
        for (int t2 = 0; t2 < 2; ++t2)
#pragma unroll
          for (int r = 0; r < 4; ++r) {
            int mloc = mt * 16 + rbase + r, col = w * 32 + t2 * 16 + m15;
            if (!ego) {
              int n = nid * 32 + mloc;
              ((float*)(wsb + B_NBRH1))[((size_t)tg * NB_ + n) * H_ + col] =
                  h1v[mt][t2][r];
            } else {
              int b = eidx * 32 + mloc;
              ((float*)(wsb + B_COMB))[((size_t)tg * B_ + b) * 512 + col] =
                  h1v[mt][t2][r];
            }
          }
    }
    __syncthreads();  // B4
  }
}

// ---------------- attention at t=48,49 (one block per (t2,b)) ----------------
__global__ __launch_bounds__(256) void attn_kernel(Par p) {
  __shared__ float kk[NN_][H_];
  __shared__ float vv[NN_][H_];
  __shared__ float e[H_];
  __shared__ float q[H_];
  __shared__ float att[H_];
  __shared__ float sc[NH_][NN_];
  const int tid = threadIdx.x;
  const int bid = blockIdx.x;
  const int t2 = bid >> 8, b = bid & 255;
  char* wsb = (char*)p.ws;
  const float* attw = (const float*)(wsb + B_ATT);
  float* comb = (float*)(wsb + B_COMB);

  e[tid] = comb[((size_t)t2 * B_ + b) * 512 + tid];
  __syncthreads();
  {
    float a = p.bq[tid];
    const float* Wq = attw + tid;
    for (int k0 = 0; k0 < H_; k0 += 4) {
      const float4 e4 = *reinterpret_cast<const float4*>(&e[k0]);
      a = fmaf(Wq[(size_t)k0 * 256], e4.x, a);
      a = fmaf(Wq[(size_t)(k0 + 1) * 256], e4.y, a);
      a = fmaf(Wq[(size_t)(k0 + 2) * 256], e4.z, a);
      a = fmaf(Wq[(size_t)(k0 + 3) * 256], e4.w, a);
    }
    q[tid] = a;
  }
  {
    float ak[NN_], av[NN_];
#pragma unroll
    for (int n = 0; n < NN_; ++n) { ak[n] = p.bk[tid]; av[n] = p.bv[tid]; }
    const float* Wk = attw + 65536 + tid;
    const float* Wv = attw + 2 * 65536 + tid;
    const float* hb = (const float*)(wsb + B_NBRH1) +
                      ((size_t)t2 * NB_ + (size_t)b * NN_) * H_;
    for (int k0 = 0; k0 < H_; k0 += 4) {
      float wk0 = Wk[(size_t)k0 * 256], wk1 = Wk[(size_t)(k0 + 1) * 256];
      float wk2 = Wk[(size_t)(k0 + 2) * 256], wk3 = Wk[(size_t)(k0 + 3) * 256];
      float wv0 = Wv[(size_t)k0 * 256], wv1 = Wv[(size_t)(k0 + 1) * 256];
      float wv2 = Wv[(size_t)(k0 + 2) * 256], wv3 = Wv[(size_t)(k0 + 3) * 256];
#pragma unroll
      for (int n = 0; n < NN_; ++n) {
        const float4 h4 =
            *reinterpret_cast<const float4*>(hb + (size_t)n * H_ + k0);
        ak[n] = fmaf(wk0, h4.x, ak[n]);
        ak[n] = fmaf(wk1, h4.y, ak[n]);
        ak[n] = fmaf(wk2, h4.z, ak[n]);
        ak[n] = fmaf(wk3, h4.w, ak[n]);
        av[n] = fmaf(wv0, h4.x, av[n]);
        av[n] = fmaf(wv1, h4.y, av[n]);
        av[n] = fmaf(wv2, h4.z, av[n]);
        av[n] = fmaf(wv3, h4.w, av[n]);
      }
    }
#pragma unroll
    for (int n = 0; n < NN_; ++n) { kk[n][tid] = ak[n]; vv[n][tid] = av[n]; }
  }
  __syncthreads();
  if (tid < NH_ * NN_) {
    int h = tid / NN_, n = tid - h * NN_;
    float s = 0.f;
#pragma unroll
    for (int d = 0; d < 32; ++d) s = fmaf(q[h * 32 + d], kk[n][h * 32 + d], s);
    sc[h][n] = s * 0.17677669529663687f;
  }
  __syncthreads();
  if (tid < NH_) {
    float mx = sc[tid][0];
#pragma unroll
    for (int n = 1; n < NN_; ++n) mx = fmaxf(mx, sc[tid][n]);
    float den = 0.f, wn[NN_];
#pragma unroll
    for (int n = 0; n < NN_; ++n) {
      wn[n] = __expf(sc[tid][n] - mx);
      den += wn[n];
    }
    float r = 1.f / den;
#pragma unroll
    for (int n = 0; n < NN_; ++n) sc[tid][n] = wn[n] * r;
  }
  __syncthreads();
  {
    int h = tid >> 5;
    float a = 0.f;
#pragma unroll
    for (int n = 0; n < NN_; ++n) a = fmaf(sc[h][n], vv[n][tid], a);
    att[tid] = a;
  }
  __syncthreads();
  {
    float a = p.bao[tid];
    const float* Wao = attw + 3 * 65536 + tid;
    for (int k0 = 0; k0 < H_; k0 += 4) {
      const float4 a4 = *reinterpret_cast<const float4*>(&att[k0]);
      a = fmaf(Wao[(size_t)k0 * 256], a4.x, a);
      a = fmaf(Wao[(size_t)(k0 + 1) * 256], a4.y, a);
      a = fmaf(Wao[(size_t)(k0 + 2) * 256], a4.z, a);
      a = fmaf(Wao[(size_t)(k0 + 3) * 256], a4.w, a);
    }
    comb[((size_t)t2 * B_ + b) * 512 + 256 + tid] = a;
  }
}

// -------- conv (only t=49 output live) + decoder layer-0 x-part --------
__global__ __launch_bounds__(256) void conv_kernel(Par p) {
  __shared__ float cl[2][512];
  __shared__ float tf[H_];
  const int b = blockIdx.x, tid = threadIdx.x;
  char* wsb = (char*)p.ws;
  const float* comb = (const float*)(wsb + B_COMB);
  for (int idx = tid; idx < 1024; idx += 256) {
    int t2 = idx >> 9, c = idx & 511;
    cl[t2][c] = comb[((size_t)t2 * B_ + b) * 512 + c];
  }
  __syncthreads();
  {
    float a = p.bconv[tid];
    const float* W0 = (const float*)(wsb + B_WCT) + tid;
    const float* W1 = W0 + 512 * 256;
    for (int c = 0; c < 512; ++c) {
      a = fmaf(cl[0][c], W0[(size_t)c * 256], a);
      a = fmaf(cl[1][c], W1[(size_t)c * 256], a);
    }
    tf[tid] = a;
  }
  __syncthreads();
  {
    float accp[4];
    const float* bcd0 = (const float*)(wsb + B_BC) + 4096;
#pragma unroll
    for (int g = 0; g < 4; ++g) accp[g] = bcd0[g * 256 + tid];
    const float* Wt = (const float*)(wsb + B_DIH0T) + tid;
    for (int k0 = 0; k0 < H_; k0 += 4) {
      const float4 t4 = *reinterpret_cast<const float4*>(&tf[k0]);
      float tv[4] = {t4.x, t4.y, t4.z, t4.w};
#pragma unroll
      for (int kq = 0; kq < 4; ++kq) {
        const float* wp = Wt + (size_t)(k0 + kq) * G_;
        accp[0] = fmaf(wp[0], tv[kq], accp[0]);
        accp[1] = fmaf(wp[256], tv[kq], accp[1]);
        accp[2] = fmaf(wp[512], tv[kq], accp[2]);
        accp[3] = fmaf(wp[768], tv[kq], accp[3]);
      }
    }
    float* pre0 = (float*)(wsb + B_PRE0);
#pragma unroll
    for (int g = 0; g < 4; ++g) pre0[(size_t)b * G_ + g * 256 + tid] = accp[g];
  }
}

// ---------------- decoder: 2-layer LSTM, 60 steps (MFMA, depth-2) + head -------
__attribute__((amdgpu_waves_per_eu(2, 2))) __global__ __launch_bounds__(512)
void decoder_kernel(Par p) {
  constexpr int MTC = 1;
  __shared__ _Float16 Hs[2][2][16][264];
  __shared__ _Float16 pad_[24576];  // push LDS >80KB -> 1 block/CU budget
  const int tid = threadIdx.x, w = tid >> 6, l = tid & 63;
  const int m15 = l & 15, khi = (l >> 4) * 8;
  const int bid = blockIdx.x;
  char* wsb = (char*)p.ws;
  const _Float16* WB_hh0 = (const _Float16*)(wsb + O_F_DHH0);
  const _Float16* WB_ih1 = (const _Float16*)(wsb + O_F_DIH1);
  const _Float16* WB_hh1 = (const _Float16*)(wsb + O_F_DHH1);

  if (tid == 0) ((volatile _Float16*)pad_)[0] = (_Float16)0.f;
  for (int i = tid; i < 2 * 2 * 16 * 264; i += 512)
    ((_Float16*)Hs)[i] = (_Float16)0.f;

  const float* bcd1 = (const float*)(wsb + B_BC) + 5120;
  float b1v[4][2];
  f32x4 pre[4][2];
  {
    const float* pre0 = (const float*)(wsb + B_PRE0);
    const int rbase = (l >> 4) * 4;
#pragma unroll
    for (int g = 0; g < 4; ++g)
#pragma unroll
      for (int t2 = 0; t2 < 2; ++t2) {
        int j = g * 256 + w * 32 + t2 * 16 + m15;
        b1v[g][t2] = bcd1[j];
#pragma unroll
        for (int r = 0; r < 4; ++r)
          pre[g][t2][r] = pre0[(size_t)(bid * 16 + rbase + r) * G_ + j];
      }
  }
  const int hm = tid >> 5, hpp = (tid >> 4) & 1, hkc = tid & 15;
  float wr[16], bo;
  {
#pragma unroll
    for (int e2 = 0; e2 < 16; ++e2) wr[e2] = p.Wout[hpp * 256 + hkc * 16 + e2];
    bo = p.bout[hpp];
  }

  f16x8 bA[8], bB[8], bC[8];
  loadB8(bA, WB_hh0, 0, w, l);
  loadB8(bB, WB_hh0, 1, w, l);
  f32x4 c0[1][2] = {}, c1[1][2] = {};
  float h0v[1][2][4], h1v[1][2][4];
  __syncthreads();

  for (int t = 0; t < DT_; ++t) {
    f32x4 acc[MTC][4][2];
#pragma unroll
    for (int g = 0; g < 4; ++g)
#pragma unroll
      for (int t2 = 0; t2 < 2; ++t2) acc[0][g][t2] = pre[g][t2];
    G8D(bA, bB, bC, WB_hh0, WB_ih1, &Hs[0][0][0][0], &Hs[0][1][0][0])
    cell_compute<MTC>(acc, c0, h0v);
    __syncthreads();  // B1
    writeH<MTC>(h0v, &Hs[0][0][0][0], &Hs[0][1][0][0], w, l);
    __syncthreads();  // B2
    acc_init<MTC>(acc, b1v);
    G8D(bC, bA, bB, WB_ih1, WB_hh1, &Hs[0][0][0][0], &Hs[0][1][0][0])
    G8D(bB, bC, bA, WB_hh1, WB_hh0, &Hs[1][0][0][0], &Hs[1][1][0][0])
    cell_compute<MTC>(acc, c1, h1v);
    __syncthreads();  // B3
    writeH<MTC>(h1v, &Hs[1][0][0][0], &Hs[1][1][0][0], w, l);
    __syncthreads();  // B4
    {  // head: pred[m][pp] = (h1hi+h1lo) . Wout[pp] + bout[pp]
      const _Float16* h1h = &Hs[1][0][hm][hkc * 16];
      const _Float16* h1l = &Hs[1][1][hm][hkc * 16];
      f16x8 a0 = *(const f16x8*)(h1h), a1 = *(const f16x8*)(h1h + 8);
      f16x8 q0 = *(const f16x8*)(h1l), q1 = *(const f16x8*)(h1l + 8);
      float s = 0.f;
#pragma unroll
      for (int e2 = 0; e2 < 8; ++e2) {
        s = fmaf((float)a0[e2] + (float)q0[e2], wr[e2], s);
        s = fmaf((float)a1[e2] + (float)q1[e2], wr[8 + e2], s);
      }
#pragma unroll
      for (int off = 1; off < 16; off <<= 1) s += __shfl_xor(s, off);
      if ((tid & 15) == 0)
        p.out[((size_t)(bid * 16 + hm) * DT_ + t) * 2 + hpp] = s + bo;
    }
  }
}

// ---------------- host launcher ----------------
extern "C" void kernel_launch(void* const* d_in, const int* in_sizes, int n_in,
                              void* d_out, int out_size, void* d_ws,
                              size_t ws_size, hipStream_t stream) {
  (void)in_sizes; (void)n_in; (void)out_size; (void)ws_size;
  auto F = [&](int i) { return (const float*)d_in[i]; };
  Par p{};
  p.x = F(0);
  p.big_src[0] = F(10);  // nbr_Whh0
  p.big_src[1] = F(13);  // nbr_Wih1
  p.big_src[2] = F(14);  // nbr_Whh1
  p.big_src[3] = F(2);   // ego_Whh0
  p.big_src[4] = F(5);   // ego_Wih1
  p.big_src[5] = F(6);   // ego_Whh1
  p.big_src[6] = F(18);  // dec_Whh0
  p.big_src[7] = F(21);  // dec_Wih1
  p.big_src[8] = F(22);  // dec_Whh1
  p.big_src[9] = F(17);  // dec_Wih0
  p.ih0_src[0] = F(9);   // nbr_Wih0
  p.ih0_src[1] = F(1);   // ego_Wih0
  p.att_src[0] = F(25); p.att_src[1] = F(26);
  p.att_src[2] = F(27); p.att_src[3] = F(28);
  p.Wconv = F(33);
  p.bih[0] = F(11); p.bhh[0] = F(12);
  p.bih[1] = F(15); p.bhh[1] = F(16);
  p.bih[2] = F(3);  p.bhh[2] = F(4);
  p.bih[3] = F(7);  p.bhh[3] = F(8);
  p.bih[4] = F(19); p.bhh[4] = F(20);
  p.bih[5] = F(23); p.bhh[5] = F(24);
  p.bq = F(29); p.bk = F(30); p.bv = F(31); p.bao = F(32);
  p.bconv = F(34); p.Wout = F(35); p.bout = F(36);
  p.ws = (float*)d_ws;
  p.out = (float*)d_out;

  hipLaunchKernelGGL(prep_kernel, dim3(1024), dim3(256), 0, stream, p);
  hipLaunchKernelGGL(encoder_kernel, dim3(NBLK_ENC), dim3(512), 0, stream, p);
  hipLaunchKernelGGL(attn_kernel, dim3(512), dim3(256), 0, stream, p);
  hipLaunchKernelGGL(conv_kernel, dim3(B_), dim3(256), 0, stream, p);
  hipLaunchKernelGGL(decoder_kernel, dim3(NBLK_DEC), dim3(512), 0, stream, p);
}

// Round 9
// 3619.678 us; speedup vs baseline: 2.0772x; 2.0772x over previous
//
#include <hip/hip_runtime.h>

#define DEV __device__ __forceinline__

typedef _Float16 f16x8 __attribute__((ext_vector_type(8)));
typedef float f32x4 __attribute__((ext_vector_type(4)));

// ---- problem dims ----
constexpr int B_ = 256, A_ = 20, T_ = 50, IN_ = 6;
constexpr int H_ = 256, G_ = 1024, NH_ = 8, DT_ = 60;
constexpr int NN_ = 19;
constexpr int NB_ = B_ * NN_;   // 4864
constexpr int XROW = T_ * IN_;  // 300

constexpr int NBLK_ENC = 160;   // 152 nbr + 8 ego (ego at bid%8==0, bid<64)
constexpr int NBLK_DEC = 16;

// ---- ws byte offsets ----
// B-fragment layout for W^T (j=gate*256+col): frag[((jt*8+kt)*64+l)*8+e]
//   = (fp16) W[n*256+k], n=jt*16+(l&15), k=kt*32+(l>>4)*8+e
constexpr size_t FB = 64ull * 8 * 64 * 8 * 2;  // 512KB per 1024x256 matrix
constexpr size_t FS = 64ull * 64 * 8 * 2;      // 64KB per 1024x6 (K pad 32)
constexpr size_t O_F_NHH0 = 0;
constexpr size_t O_F_NIH1 = O_F_NHH0 + FB;
constexpr size_t O_F_NHH1 = O_F_NIH1 + FB;
constexpr size_t O_F_EHH0 = O_F_NHH1 + FB;
constexpr size_t O_F_EIH1 = O_F_EHH0 + FB;
constexpr size_t O_F_EHH1 = O_F_EIH1 + FB;
constexpr size_t O_F_DHH0 = O_F_EHH1 + FB;
constexpr size_t O_F_DIH1 = O_F_DHH0 + FB;
constexpr size_t O_F_DHH1 = O_F_DIH1 + FB;
constexpr size_t O_F_NIH0 = O_F_DHH1 + FB;
constexpr size_t O_F_EIH0 = O_F_NIH0 + FS;
constexpr size_t B_BC    = O_F_EIH0 + FS;            // 6*1024 fp32
constexpr size_t B_ATT   = B_BC + 6 * 1024 * 4;      // 4 x [k][256] fp32
constexpr size_t B_WCT   = B_ATT + 4 * 65536 * 4;    // [2][512][256] fp32
constexpr size_t B_DIH0T = B_WCT + 2 * 512 * 256 * 4;// [k][1024] fp32
constexpr size_t B_NBRH1 = B_DIH0T + 256 * 1024 * 4; // [2][4864][256] fp32
constexpr size_t B_COMB  = B_NBRH1 + 2ull * NB_ * H_ * 4;  // [2][256][512]
constexpr size_t B_PRE0  = B_COMB + 2ull * B_ * 512 * 4;   // [256][1024]

struct Par {
  const float* x;
  const float* big_src[10];
  const float* ih0_src[2];
  const float* att_src[4];
  const float* Wconv;
  const float* bih[6];
  const float* bhh[6];
  const float *bq, *bk, *bv, *bao, *bconv, *Wout, *bout;
  float* ws;
  float* out;
};

// ---------------- prep: fragment packing + transposes + bias sums ----------------
__global__ void prep_kernel(Par p) {
  char* wsb = (char*)p.ws;
  const size_t NBIG = 9ull * 262144;
  const size_t NIH0 = 2ull * 32768;
  const size_t NBC  = 6144;
  const size_t NATT = 4ull * 65536;
  const size_t NWCT = 2ull * 512 * 256;
  const size_t NDIH = 256ull * 1024;
  const size_t total = NBIG + NIH0 + NBC + NATT + NWCT + NDIH;
  for (size_t i = (size_t)blockIdx.x * blockDim.x + threadIdx.x; i < total;
       i += (size_t)gridDim.x * blockDim.x) {
    size_t idx = i;
    if (idx < NBIG) {
      int mi = (int)(idx / 262144);
      size_t f = idx - (size_t)mi * 262144;
      int e = (int)(f & 7), l = (int)((f >> 3) & 63);
      int kt = (int)((f >> 9) & 7), jt = (int)(f >> 12);
      int n = jt * 16 + (l & 15), k = kt * 32 + (l >> 4) * 8 + e;
      ((_Float16*)(wsb + O_F_NHH0))[idx] =
          (_Float16)p.big_src[mi][(size_t)n * 256 + k];
      continue;
    }
    idx -= NBIG;
    if (idx < NIH0) {
      int mi = (int)(idx >> 15);
      size_t f = idx & 32767;
      int e = (int)(f & 7), l = (int)((f >> 3) & 63), jt = (int)(f >> 9);
      int n = jt * 16 + (l & 15), k = (l >> 4) * 8 + e;
      ((_Float16*)(wsb + O_F_NIH0))[idx] =
          (_Float16)(k < 6 ? p.ih0_src[mi][(size_t)n * 6 + k] : 0.f);
      continue;
    }
    idx -= NIH0;
    if (idx < NBC) {
      int li = (int)(idx >> 10), jj = (int)(idx & 1023);
      ((float*)(wsb + B_BC))[idx] = p.bih[li][jj] + p.bhh[li][jj];
      continue;
    }
    idx -= NBC;
    if (idx < NATT) {
      int mi = (int)(idx >> 16);
      size_t f = idx & 65535;
      int k = (int)(f >> 8), c = (int)(f & 255);
      ((float*)(wsb + B_ATT))[idx] = p.att_src[mi][(size_t)c * 256 + k];
      continue;
    }
    idx -= NATT;
    if (idx < NWCT) {
      int dt = (int)(idx / (512 * 256));
      size_t f = idx - (size_t)dt * 512 * 256;
      int c = (int)(f >> 8), o = (int)(f & 255);
      ((float*)(wsb + B_WCT))[idx] = p.Wconv[(size_t)o * 1536 + (size_t)c * 3 + dt];
      continue;
    }
    idx -= NWCT;
    {
      int k = (int)(idx >> 10), j = (int)(idx & 1023);
      ((float*)(wsb + B_DIH0T))[idx] = p.big_src[9][(size_t)j * 256 + k];
    }
  }
}

// ---------------- building blocks ----------------
DEV float fsig(float x) { return 1.f / (1.f + __expf(-x)); }
DEV float ftanh(float x) { return 1.f - 2.f / (__expf(2.f * x) + 1.f); }

DEV void gl_lds16(const void* g, void* l) {
  __builtin_amdgcn_global_load_lds(
      (const __attribute__((address_space(1))) void*)g,
      (__attribute__((address_space(3))) void*)l, 16, 0, 0);
}

template <int MT>
DEV void acc_init(f32x4 (&acc)[MT][4][2], const float (&b)[4][2]) {
#pragma unroll
  for (int mt = 0; mt < MT; ++mt)
#pragma unroll
    for (int g = 0; g < 4; ++g)
#pragma unroll
      for (int t2 = 0; t2 < 2; ++t2) {
        f32x4 v = {b[g][t2], b[g][t2], b[g][t2], b[g][t2]};
        acc[mt][g][t2] = v;
      }
}

template <int MT>
DEV void cell_compute(f32x4 (&acc)[MT][4][2], f32x4 (&c)[MT][2],
                      float (&hv)[MT][2][4]) {
#pragma unroll
  for (int mt = 0; mt < MT; ++mt)
#pragma unroll
    for (int t2 = 0; t2 < 2; ++t2)
#pragma unroll
      for (int r = 0; r < 4; ++r) {
        float iv = fsig(acc[mt][0][t2][r]);
        float fv = fsig(acc[mt][1][t2][r]);
        float gv = ftanh(acc[mt][2][t2][r]);
        float ov = fsig(acc[mt][3][t2][r]);
        float cv = fv * c[mt][t2][r] + iv * gv;
        c[mt][t2][r] = cv;
        hv[mt][t2][r] = ov * ftanh(cv);
      }
}

template <int MT>
DEV void writeH(const float (&hv)[MT][2][4], _Float16* Hhi, _Float16* Hlo,
                int w, int l) {
  const int rbase = (l >> 4) * 4, m15 = l & 15;
#pragma unroll
  for (int mt = 0; mt < MT; ++mt)
#pragma unroll
    for (int t2 = 0; t2 < 2; ++t2)
#pragma unroll
      for (int r = 0; r < 4; ++r) {
        int m = mt * 16 + rbase + r, col = w * 32 + t2 * 16 + m15;
        float hvv = hv[mt][t2][r];
        _Float16 hi = (_Float16)hvv;
        Hhi[m * 264 + col] = hi;
        Hlo[m * 264 + col] = (_Float16)(hvv - (float)hi);
      }
}

// consume one staged half-chunk (4 B-frags) against A frags ah/al (hi/lo h)
template <int MT, int HALF>
DEV void cons_h(f32x4 (&acc)[MT][4][2], const _Float16* bsw,
                const f16x8 (&ah)[MT], const f16x8 (&al)[MT]) {
#pragma unroll
  for (int qq = 0; qq < 4; ++qq) {
    const int q = HALF * 4 + qq, g = q >> 1, t2 = q & 1;
    f16x8 b = *(const f16x8*)(bsw + qq * 512);
#pragma unroll
    for (int mt = 0; mt < MT; ++mt) {
      acc[mt][g][t2] = __builtin_amdgcn_mfma_f32_16x16x32_f16(
          ah[mt], b, acc[mt][g][t2], 0, 0, 0);
      acc[mt][g][t2] = __builtin_amdgcn_mfma_f32_16x16x32_f16(
          al[mt], b, acc[mt][g][t2], 0, 0, 0);
    }
  }
}
template <int HALF>
DEV void cons_ih0(f32x4 (&acc)[2][4][2], const _Float16* bsw, f16x8 a0,
                  f16x8 a1) {
#pragma unroll
  for (int qq = 0; qq < 4; ++qq) {
    const int q = HALF * 4 + qq, g = q >> 1, t2 = q & 1;
    f16x8 b = *(const f16x8*)(bsw + qq * 512);
    acc[0][g][t2] = __builtin_amdgcn_mfma_f32_16x16x32_f16(a0, b, acc[0][g][t2], 0, 0, 0);
    acc[1][g][t2] = __builtin_amdgcn_mfma_f32_16x16x32_f16(a1, b, acc[1][g][t2], 0, 0, 0);
  }
}

#define WAIT_VM0 asm volatile("s_waitcnt vmcnt(0)" ::: "memory")

// ---------------- encoder: fused ego+nbr 2-layer LSTM ----------------
// Weight B-fragments stream global->LDS via global_load_lds (no VGPR cost,
// deep queue). Per half-chunk: wait vmcnt(0); issue next 4 frags into the
// alternate per-wave LDS buffer; consume current (4 ds_read_b128 + 16 MFMA
// covers the in-flight L2 latency). 50 half-chunks/step.
__global__ __launch_bounds__(512) void encoder_kernel(Par p) {
  __shared__ _Float16 Hs[2][2][32][264];  // [layer][hi/lo][m][k pad]
  __shared__ _Float16 XF[2][512];         // x A-frags (K pad 32)
  __shared__ _Float16 BS[8][2][2048];     // [wave][buf][4 frags x 64 lanes x 8]
  const int tid = threadIdx.x, w = tid >> 6, l = tid & 63;
  const int m15 = l & 15, khi = (l >> 4) * 8;
  const int bid = blockIdx.x;
  const bool ego = ((bid & 7) == 0) && (bid < 64);
  int nid = 0, eidx = 0;
  if (ego) {
    eidx = bid >> 3;
  } else {
    int nb = (bid + 7) >> 3;
    if (nb > 8) nb = 8;
    nid = bid - nb;
  }
  char* wsb = (char*)p.ws;
  // per-lane weight base pointers (lane offset l*16B baked in)
  const char* WBl_hh0 = wsb + (ego ? O_F_EHH0 : O_F_NHH0) + (size_t)l * 16;
  const char* WBl_ih1 = wsb + (ego ? O_F_EIH1 : O_F_NIH1) + (size_t)l * 16;
  const char* WBl_hh1 = wsb + (ego ? O_F_EHH1 : O_F_NHH1) + (size_t)l * 16;
  const char* WBl_ih0 = wsb + (ego ? O_F_EIH0 : O_F_NIH0) + (size_t)l * 16;

  for (int i = tid; i < 2 * 2 * 32 * 264; i += 512)
    ((_Float16*)Hs)[i] = (_Float16)0.f;
  for (int i = tid; i < 1024; i += 512) ((_Float16*)XF)[i] = (_Float16)0.f;

  const float* bcb = (const float*)(wsb + B_BC) + (ego ? 2048 : 0);
  float b0v[4][2], b1v[4][2];
#pragma unroll
  for (int g = 0; g < 4; ++g)
#pragma unroll
    for (int t2 = 0; t2 < 2; ++t2) {
      int j = g * 256 + w * 32 + t2 * 16 + m15;
      b0v[g][t2] = bcb[j];
      b1v[g][t2] = bcb[1024 + j];
    }

  // x staging: tid<192 -> (m32 0..31, kx 0..5)
  const int m32 = tid / 6, kx = tid - m32 * 6;
  const float* xp = nullptr;
  int xslot = 0;
  if (tid < 192) {
    int row;
    if (!ego) {
      int n = nid * 32 + m32;
      int q = n / 19;
      row = q * 20 + 1 + (n - q * 19);
    } else {
      row = (eidx * 32 + m32) * 20;
    }
    xp = p.x + (size_t)row * XROW + kx;
    xslot = (m32 >> 4) * 512 + (m32 & 15) * 8 + kx;
  }

  // issue slot s (0..49) into BS[w][dbuf]
  auto issue_slot = [&](int s, int dbuf) {
    const char* WBl;
    int kt, half;
    bool ih0m = false;
    if (s < 2) { WBl = WBl_ih0; kt = 0; half = s; ih0m = true; }
    else if (s < 18) { int e = s - 2;  WBl = WBl_hh0; kt = e >> 1; half = e & 1; }
    else if (s < 34) { int e = s - 18; WBl = WBl_ih1; kt = e >> 1; half = e & 1; }
    else             { int e = s - 34; WBl = WBl_hh1; kt = e >> 1; half = e & 1; }
#pragma unroll
    for (int qq = 0; qq < 4; ++qq) {
      int q = half * 4 + qq;
      int jt = (q >> 1) * 16 + w * 2 + (q & 1);
      size_t off = ih0m ? (size_t)jt * 1024 : (size_t)(jt * 8 + kt) * 1024;
      gl_lds16(WBl + off, &BS[w][dbuf][qq * 512]);
    }
  };

  __syncthreads();
  if (tid < 192) ((_Float16*)XF)[xslot] = (_Float16)xp[0];
  issue_slot(0, 0);  // prologue; barrier below drains it resident
  __syncthreads();

  f32x4 c0[2][2] = {}, c1[2][2] = {};
  float h0v[2][2][4], h1v[2][2][4];
  f16x8 ah[2], al[2];
  f16x8 a0{}, a1{};
  int buf = 0;

  for (int t = 0; t < T_; ++t) {
    // ---- layer 0: slots 0..17 (ih0 x2, hh0 x16) ----
    f32x4 acc[2][4][2];
    acc_init<2>(acc, b0v);
    for (int s = 0; s < 18; ++s) {
      WAIT_VM0;
      issue_slot(s + 1, buf ^ 1);
      const _Float16* bsw = &BS[w][buf][0] + (size_t)l * 8;
      if (s < 2) {
        if (s == 0) {
          a0 = *(const f16x8*)(&XF[0][l * 8]);
          a1 = *(const f16x8*)(&XF[1][l * 8]);
          cons_ih0<0>(acc, bsw, a0, a1);
        } else {
          cons_ih0<1>(acc, bsw, a0, a1);
        }
      } else {
        int e = s - 2, kt = e >> 1;
        if ((e & 1) == 0) {
#pragma unroll
          for (int mt = 0; mt < 2; ++mt) {
            int off = (mt * 16 + m15) * 264 + kt * 32 + khi;
            ah[mt] = *(const f16x8*)(&Hs[0][0][0][0] + off);
            al[mt] = *(const f16x8*)(&Hs[0][1][0][0] + off);
          }
          cons_h<2, 0>(acc, bsw, ah, al);
        } else {
          cons_h<2, 1>(acc, bsw, ah, al);
        }
      }
      buf ^= 1;
    }
    cell_compute<2>(acc, c0, h0v);
    __syncthreads();  // B1: all reads of Hs[0] done
    writeH<2>(h0v, &Hs[0][0][0][0], &Hs[0][1][0][0], w, l);
    if (t < T_ - 1 && tid < 192)
      ((_Float16*)XF)[xslot] = (_Float16)xp[(t + 1) * IN_];
    __syncthreads();  // B2: h0_new + x_{t+1} visible

    // ---- layer 1: slots 18..49 (ih1 x16 on h0_new, hh1 x16 on h1_old) ----
    acc_init<2>(acc, b1v);
    for (int s = 18; s < 50; ++s) {
      WAIT_VM0;
      issue_slot(s + 1 == 50 ? 0 : s + 1, buf ^ 1);
      const _Float16* bsw = &BS[w][buf][0] + (size_t)l * 8;
      int e = s - 18;
      const _Float16 *Hh, *Hl;
      int ee;
      if (e < 16) { ee = e;      Hh = &Hs[0][0][0][0]; Hl = &Hs[0][1][0][0]; }
      else        { ee = e - 16; Hh = &Hs[1][0][0][0]; Hl = &Hs[1][1][0][0]; }
      int kt = ee >> 1;
      if ((ee & 1) == 0) {
#pragma unroll
        for (int mt = 0; mt < 2; ++mt) {
          int off = (mt * 16 + m15) * 264 + kt * 32 + khi;
          ah[mt] = *(const f16x8*)(Hh + off);
          al[mt] = *(const f16x8*)(Hl + off);
        }
        cons_h<2, 0>(acc, bsw, ah, al);
      } else {
        cons_h<2, 1>(acc, bsw, ah, al);
      }
      buf ^= 1;
    }
    cell_compute<2>(acc, c1, h1v);
    __syncthreads();  // B3: reads of Hs[1] done
    writeH<2>(h1v, &Hs[1][0][0][0], &Hs[1][1][0][0], w, l);
    if (t >= T_ - 2) {  // only t=48,49 consumed downstream
      int tg = t - (T_ - 2);
      const int rbase = (l >> 4) * 4;
#pragma unroll
      for (int mt = 0; mt < 2; ++mt)
#pragma unroll
        for (int t2 = 0; t2 < 2; ++t2)
#pragma unroll
          for (int r = 0; r < 4; ++r) {
            int mloc = mt * 16 + rbase + r, col = w * 32 + t2 * 16 + m15;
            if (!ego) {
              int n = nid * 32 + mloc;
              ((float*)(wsb + B_NBRH1))[((size_t)tg * NB_ + n) * H_ + col] =
                  h1v[mt][t2][r];
            } else {
              int b = eidx * 32 + mloc;
              ((float*)(wsb + B_COMB))[((size_t)tg * B_ + b) * 512 + col] =
                  h1v[mt][t2][r];
            }
          }
    }
    __syncthreads();  // B4
  }
}

// ---------------- attention at t=48,49 (one block per (t2,b)) ----------------
__global__ __launch_bounds__(256) void attn_kernel(Par p) {
  __shared__ float kk[NN_][H_];
  __shared__ float vv[NN_][H_];
  __shared__ float e[H_];
  __shared__ float q[H_];
  __shared__ float att[H_];
  __shared__ float sc[NH_][NN_];
  const int tid = threadIdx.x;
  const int bid = blockIdx.x;
  const int t2 = bid >> 8, b = bid & 255;
  char* wsb = (char*)p.ws;
  const float* attw = (const float*)(wsb + B_ATT);
  float* comb = (float*)(wsb + B_COMB);

  e[tid] = comb[((size_t)t2 * B_ + b) * 512 + tid];
  __syncthreads();
  {
    float a = p.bq[tid];
    const float* Wq = attw + tid;
    for (int k0 = 0; k0 < H_; k0 += 4) {
      const float4 e4 = *reinterpret_cast<const float4*>(&e[k0]);
      a = fmaf(Wq[(size_t)k0 * 256], e4.x, a);
      a = fmaf(Wq[(size_t)(k0 + 1) * 256], e4.y, a);
      a = fmaf(Wq[(size_t)(k0 + 2) * 256], e4.z, a);
      a = fmaf(Wq[(size_t)(k0 + 3) * 256], e4.w, a);
    }
    q[tid] = a;
  }
  {
    float ak[NN_], av[NN_];
#pragma unroll
    for (int n = 0; n < NN_; ++n) { ak[n] = p.bk[tid]; av[n] = p.bv[tid]; }
    const float* Wk = attw + 65536 + tid;
    const float* Wv = attw + 2 * 65536 + tid;
    const float* hb = (const float*)(wsb + B_NBRH1) +
                      ((size_t)t2 * NB_ + (size_t)b * NN_) * H_;
    for (int k0 = 0; k0 < H_; k0 += 4) {
      float wk0 = Wk[(size_t)k0 * 256], wk1 = Wk[(size_t)(k0 + 1) * 256];
      float wk2 = Wk[(size_t)(k0 + 2) * 256], wk3 = Wk[(size_t)(k0 + 3) * 256];
      float wv0 = Wv[(size_t)k0 * 256], wv1 = Wv[(size_t)(k0 + 1) * 256];
      float wv2 = Wv[(size_t)(k0 + 2) * 256], wv3 = Wv[(size_t)(k0 + 3) * 256];
#pragma unroll
      for (int n = 0; n < NN_; ++n) {
        const float4 h4 =
            *reinterpret_cast<const float4*>(hb + (size_t)n * H_ + k0);
        ak[n] = fmaf(wk0, h4.x, ak[n]);
        ak[n] = fmaf(wk1, h4.y, ak[n]);
        ak[n] = fmaf(wk2, h4.z, ak[n]);
        ak[n] = fmaf(wk3, h4.w, ak[n]);
        av[n] = fmaf(wv0, h4.x, av[n]);
        av[n] = fmaf(wv1, h4.y, av[n]);
        av[n] = fmaf(wv2, h4.z, av[n]);
        av[n] = fmaf(wv3, h4.w, av[n]);
      }
    }
#pragma unroll
    for (int n = 0; n < NN_; ++n) { kk[n][tid] = ak[n]; vv[n][tid] = av[n]; }
  }
  __syncthreads();
  if (tid < NH_ * NN_) {
    int h = tid / NN_, n = tid - h * NN_;
    float s = 0.f;
#pragma unroll
    for (int d = 0; d < 32; ++d) s = fmaf(q[h * 32 + d], kk[n][h * 32 + d], s);
    sc[h][n] = s * 0.17677669529663687f;
  }
  __syncthreads();
  if (tid < NH_) {
    float mx = sc[tid][0];
#pragma unroll
    for (int n = 1; n < NN_; ++n) mx = fmaxf(mx, sc[tid][n]);
    float den = 0.f, wn[NN_];
#pragma unroll
    for (int n = 0; n < NN_; ++n) {
      wn[n] = __expf(sc[tid][n] - mx);
      den += wn[n];
    }
    float r = 1.f / den;
#pragma unroll
    for (int n = 0; n < NN_; ++n) sc[tid][n] = wn[n] * r;
  }
  __syncthreads();
  {
    int h = tid >> 5;
    float a = 0.f;
#pragma unroll
    for (int n = 0; n < NN_; ++n) a = fmaf(sc[h][n], vv[n][tid], a);
    att[tid] = a;
  }
  __syncthreads();
  {
    float a = p.bao[tid];
    const float* Wao = attw + 3 * 65536 + tid;
    for (int k0 = 0; k0 < H_; k0 += 4) {
      const float4 a4 = *reinterpret_cast<const float4*>(&att[k0]);
      a = fmaf(Wao[(size_t)k0 * 256], a4.x, a);
      a = fmaf(Wao[(size_t)(k0 + 1) * 256], a4.y, a);
      a = fmaf(Wao[(size_t)(k0 + 2) * 256], a4.z, a);
      a = fmaf(Wao[(size_t)(k0 + 3) * 256], a4.w, a);
    }
    comb[((size_t)t2 * B_ + b) * 512 + 256 + tid] = a;
  }
}

// -------- conv (only t=49 output live) + decoder layer-0 x-part --------
__global__ __launch_bounds__(256) void conv_kernel(Par p) {
  __shared__ float cl[2][512];
  __shared__ float tf[H_];
  const int b = blockIdx.x, tid = threadIdx.x;
  char* wsb = (char*)p.ws;
  const float* comb = (const float*)(wsb + B_COMB);
  for (int idx = tid; idx < 1024; idx += 256) {
    int t2 = idx >> 9, c = idx & 511;
    cl[t2][c] = comb[((size_t)t2 * B_ + b) * 512 + c];
  }
  __syncthreads();
  {
    float a = p.bconv[tid];
    const float* W0 = (const float*)(wsb + B_WCT) + tid;
    const float* W1 = W0 + 512 * 256;
    for (int c = 0; c < 512; ++c) {
      a = fmaf(cl[0][c], W0[(size_t)c * 256], a);
      a = fmaf(cl[1][c], W1[(size_t)c * 256], a);
    }
    tf[tid] = a;
  }
  __syncthreads();
  {
    float accp[4];
    const float* bcd0 = (const float*)(wsb + B_BC) + 4096;
#pragma unroll
    for (int g = 0; g < 4; ++g) accp[g] = bcd0[g * 256 + tid];
    const float* Wt = (const float*)(wsb + B_DIH0T) + tid;
    for (int k0 = 0; k0 < H_; k0 += 4) {
      const float4 t4 = *reinterpret_cast<const float4*>(&tf[k0]);
      float tv[4] = {t4.x, t4.y, t4.z, t4.w};
#pragma unroll
      for (int kq = 0; kq < 4; ++kq) {
        const float* wp = Wt + (size_t)(k0 + kq) * G_;
        accp[0] = fmaf(wp[0], tv[kq], accp[0]);
        accp[1] = fmaf(wp[256], tv[kq], accp[1]);
        accp[2] = fmaf(wp[512], tv[kq], accp[2]);
        accp[3] = fmaf(wp[768], tv[kq], accp[3]);
      }
    }
    float* pre0 = (float*)(wsb + B_PRE0);
#pragma unroll
    for (int g = 0; g < 4; ++g) pre0[(size_t)b * G_ + g * 256 + tid] = accp[g];
  }
}

// ---------------- decoder: 2-layer LSTM, 60 steps + head ----------------
__global__ __launch_bounds__(512) void decoder_kernel(Par p) {
  __shared__ _Float16 Hs[2][2][16][264];
  __shared__ _Float16 BS[8][2][2048];
  const int tid = threadIdx.x, w = tid >> 6, l = tid & 63;
  const int m15 = l & 15, khi = (l >> 4) * 8;
  const int bid = blockIdx.x;
  char* wsb = (char*)p.ws;
  const char* WBl_hh0 = wsb + O_F_DHH0 + (size_t)l * 16;
  const char* WBl_ih1 = wsb + O_F_DIH1 + (size_t)l * 16;
  const char* WBl_hh1 = wsb + O_F_DHH1 + (size_t)l * 16;

  for (int i = tid; i < 2 * 2 * 16 * 264; i += 512)
    ((_Float16*)Hs)[i] = (_Float16)0.f;

  const float* bcd1 = (const float*)(wsb + B_BC) + 5120;
  float b1v[4][2];
  f32x4 pre[4][2];
  {
    const float* pre0 = (const float*)(wsb + B_PRE0);
    const int rbase = (l >> 4) * 4;
#pragma unroll
    for (int g = 0; g < 4; ++g)
#pragma unroll
      for (int t2 = 0; t2 < 2; ++t2) {
        int j = g * 256 + w * 32 + t2 * 16 + m15;
        b1v[g][t2] = bcd1[j];
#pragma unroll
        for (int r = 0; r < 4; ++r)
          pre[g][t2][r] = pre0[(size_t)(bid * 16 + rbase + r) * G_ + j];
      }
  }
  const int hm = tid >> 5, hpp = (tid >> 4) & 1, hkc = tid & 15;
  float wr[16], bo;
  {
#pragma unroll
    for (int e2 = 0; e2 < 16; ++e2) wr[e2] = p.Wout[hpp * 256 + hkc * 16 + e2];
    bo = p.bout[hpp];
  }

  // slot s (0..47): hh0 x16, ih1 x16, hh1 x16
  auto issue_slot = [&](int s, int dbuf) {
    const char* WBl;
    int e;
    if (s < 16)      { WBl = WBl_hh0; e = s; }
    else if (s < 32) { WBl = WBl_ih1; e = s - 16; }
    else             { WBl = WBl_hh1; e = s - 32; }
    int kt = e >> 1, half = e & 1;
#pragma unroll
    for (int qq = 0; qq < 4; ++qq) {
      int q = half * 4 + qq;
      int jt = (q >> 1) * 16 + w * 2 + (q & 1);
      gl_lds16(WBl + (size_t)(jt * 8 + kt) * 1024, &BS[w][dbuf][qq * 512]);
    }
  };

  issue_slot(0, 0);
  __syncthreads();

  f32x4 c0[1][2] = {}, c1[1][2] = {};
  float h0v[1][2][4], h1v[1][2][4];
  f16x8 ah[1], al[1];
  int buf = 0;

  for (int t = 0; t < DT_; ++t) {
    // ---- layer 0: slots 0..15 (hh0 on h0_old; x-part preloaded in regs) ----
    f32x4 acc[1][4][2];
#pragma unroll
    for (int g = 0; g < 4; ++g)
#pragma unroll
      for (int t2 = 0; t2 < 2; ++t2) acc[0][g][t2] = pre[g][t2];
    for (int s = 0; s < 16; ++s) {
      WAIT_VM0;
      issue_slot(s + 1, buf ^ 1);
      const _Float16* bsw = &BS[w][buf][0] + (size_t)l * 8;
      int kt = s >> 1;
      if ((s & 1) == 0) {
        int off = m15 * 264 + kt * 32 + khi;
        ah[0] = *(const f16x8*)(&Hs[0][0][0][0] + off);
        al[0] = *(const f16x8*)(&Hs[0][1][0][0] + off);
        cons_h<1, 0>(acc, bsw, ah, al);
      } else {
        cons_h<1, 1>(acc, bsw, ah, al);
      }
      buf ^= 1;
    }
    cell_compute<1>(acc, c0, h0v);
    __syncthreads();  // B1
    writeH<1>(h0v, &Hs[0][0][0][0], &Hs[0][1][0][0], w, l);
    __syncthreads();  // B2

    // ---- layer 1: slots 16..47 ----
    acc_init<1>(acc, b1v);
    for (int s = 16; s < 48; ++s) {
      WAIT_VM0;
      issue_slot(s + 1 == 48 ? 0 : s + 1, buf ^ 1);
      const _Float16* bsw = &BS[w][buf][0] + (size_t)l * 8;
      int e = s - 16;
      const _Float16 *Hh, *Hl;
      int ee;
      if (e < 16) { ee = e;      Hh = &Hs[0][0][0][0]; Hl = &Hs[0][1][0][0]; }
      else        { ee = e - 16; Hh = &Hs[1][0][0][0]; Hl = &Hs[1][1][0][0]; }
      int kt = ee >> 1;
      if ((ee & 1) == 0) {
        int off = m15 * 264 + kt * 32 + khi;
        ah[0] = *(const f16x8*)(Hh + off);
        al[0] = *(const f16x8*)(Hl + off);
        cons_h<1, 0>(acc, bsw, ah, al);
      } else {
        cons_h<1, 1>(acc, bsw, ah, al);
      }
      buf ^= 1;
    }
    cell_compute<1>(acc, c1, h1v);
    __syncthreads();  // B3
    writeH<1>(h1v, &Hs[1][0][0][0], &Hs[1][1][0][0], w, l);
    __syncthreads();  // B4
    {  // head: pred[m][pp] = (h1hi+h1lo) . Wout[pp] + bout[pp]
      const _Float16* h1h = &Hs[1][0][hm][hkc * 16];
      const _Float16* h1l = &Hs[1][1][hm][hkc * 16];
      f16x8 a0 = *(const f16x8*)(h1h), a1 = *(const f16x8*)(h1h + 8);
      f16x8 q0 = *(const f16x8*)(h1l), q1 = *(const f16x8*)(h1l + 8);
      float s = 0.f;
#pragma unroll
      for (int e2 = 0; e2 < 8; ++e2) {
        s = fmaf((float)a0[e2] + (float)q0[e2], wr[e2], s);
        s = fmaf((float)a1[e2] + (float)q1[e2], wr[8 + e2], s);
      }
#pragma unroll
      for (int off = 1; off < 16; off <<= 1) s += __shfl_xor(s, off);
      if ((tid & 15) == 0)
        p.out[((size_t)(bid * 16 + hm) * DT_ + t) * 2 + hpp] = s + bo;
    }
  }
}

// ---------------- host launcher ----------------
extern "C" void kernel_launch(void* const* d_in, const int* in_sizes, int n_in,
                              void* d_out, int out_size, void* d_ws,
                              size_t ws_size, hipStream_t stream) {
  (void)in_sizes; (void)n_in; (void)out_size; (void)ws_size;
  auto F = [&](int i) { return (const float*)d_in[i]; };
  Par p{};
  p.x = F(0);
  p.big_src[0] = F(10);  // nbr_Whh0
  p.big_src[1] = F(13);  // nbr_Wih1
  p.big_src[2] = F(14);  // nbr_Whh1
  p.big_src[3] = F(2);   // ego_Whh0
  p.big_src[4] = F(5);   // ego_Wih1
  p.big_src[5] = F(6);   // ego_Whh1
  p.big_src[6] = F(18);  // dec_Whh0
  p.big_src[7] = F(21);  // dec_Wih1
  p.big_src[8] = F(22);  // dec_Whh1
  p.big_src[9] = F(17);  // dec_Wih0
  p.ih0_src[0] = F(9);   // nbr_Wih0
  p.ih0_src[1] = F(1);   // ego_Wih0
  p.att_src[0] = F(25); p.att_src[1] = F(26);
  p.att_src[2] = F(27); p.att_src[3] = F(28);
  p.Wconv = F(33);
  p.bih[0] = F(11); p.bhh[0] = F(12);
  p.bih[1] = F(15); p.bhh[1] = F(16);
  p.bih[2] = F(3);  p.bhh[2] = F(4);
  p.bih[3] = F(7);  p.bhh[3] = F(8);
  p.bih[4] = F(19); p.bhh[4] = F(20);
  p.bih[5] = F(23); p.bhh[5] = F(24);
  p.bq = F(29); p.bk = F(30); p.bv = F(31); p.bao = F(32);
  p.bconv = F(34); p.Wout = F(35); p.bout = F(36);
  p.ws = (float*)d_ws;
  p.out = (float*)d_out;

  hipLaunchKernelGGL(prep_kernel, dim3(1024), dim3(256), 0, stream, p);
  hipLaunchKernelGGL(encoder_kernel, dim3(NBLK_ENC), dim3(512), 0, stream, p);
  hipLaunchKernelGGL(attn_kernel, dim3(512), dim3(256), 0, stream, p);
  hipLaunchKernelGGL(conv_kernel, dim3(B_), dim3(256), 0, stream, p);
  hipLaunchKernelGGL(decoder_kernel, dim3(NBLK_DEC), dim3(512), 0, stream, p);
}